// Round 6
// baseline (697.788 us; speedup 1.0000x reference)
//
#include <hip/hip_runtime.h>

#define N_NODES  50000
#define N_EDGES  1600000
#define N_FEAT   50
#define HID      20
#define OUT_DIM  10
#define N_GRAPHS 64

#define NBUCK 196            // coarse buckets: dst >> 8 (256 nodes each)
#define BCAP  10240          // padded slots/bucket (avg 8163, ~23 sigma margin)
#define EPB   (N_EDGES/256)  // 6250 edges per scatter block
#define NGRP  204            // 5-lane groups per 1024-thread block

// ---------------- Layer-1 GEMM (+ fused global init in blocks 0/1) ----------------

__global__ __launch_bounds__(256) void gemm50(const float* __restrict__ x,
        const float* __restrict__ Wrel, const float* __restrict__ Wroot,
        const float* __restrict__ b,
        float* __restrict__ y, float* __restrict__ acc,
        int* __restrict__ gcur, float* __restrict__ gmax,
        float* __restrict__ gsum, float* __restrict__ gcnt) {
    // fused init (runs before bucket_scatter / bgather_pool via stream order)
    if (blockIdx.x == 0) {
        if (threadIdx.x < NBUCK) gcur[threadIdx.x] = threadIdx.x * BCAP;
    } else if (blockIdx.x == 1) {
        for (int i = threadIdx.x; i < N_GRAPHS * HID; i += 256) {
            gmax[i] = 0.f; gsum[i] = 0.f;
        }
        if (threadIdx.x < N_GRAPHS) gcnt[threadIdx.x] = 0.f;
    }
    __shared__ float sWrel[N_FEAT * HID];
    __shared__ float sWroot[N_FEAT * HID];
    for (int i = threadIdx.x; i < N_FEAT * HID; i += 256) {
        sWrel[i]  = Wrel[i];
        sWroot[i] = Wroot[i];
    }
    __syncthreads();
    int idx = blockIdx.x * 256 + threadIdx.x;
    if (idx >= N_NODES * HID) return;
    int n = idx / HID, j = idx % HID;
    const float* xr = x + n * N_FEAT;
    float a0 = 0.0f, a1 = b[j];
    #pragma unroll
    for (int k = 0; k < N_FEAT; ++k) {
        float xv = xr[k];
        a0 = fmaf(xv, sWrel[k * HID + j], a0);
        a1 = fmaf(xv, sWroot[k * HID + j], a1);
    }
    y[idx]   = a0;
    acc[idx] = a1;
}

// ---------------- Bucket scatter: group edges by dst>>8, coalesced writes ----------

__global__ __launch_bounds__(1024) void bucket_scatter(const int* __restrict__ dst,
        const int* __restrict__ src, int* __restrict__ gcur,
        unsigned int* __restrict__ padded) {
    __shared__ unsigned int ep[EPB];
    __shared__ unsigned int ep2[EPB];
    __shared__ int cnt[256];
    __shared__ int scn[256];
    __shared__ int lofs[256];
    __shared__ int gbase[256];
    __shared__ int lcur[256];
    int t = threadIdx.x;
    if (t < 256) cnt[t] = 0;
    __syncthreads();
    int e0 = blockIdx.x * EPB;
    for (int i = t; i < EPB; i += 1024) {
        int d = dst[e0 + i];
        int s = src[e0 + i];
        ep[i] = ((unsigned int)d << 16) | (unsigned int)s;
        atomicAdd(&cnt[d >> 8], 1);
    }
    __syncthreads();
    if (t < 256) scn[t] = cnt[t];
    __syncthreads();
    for (int d = 1; d < 256; d <<= 1) {
        int u = 0;
        if (t < 256 && t >= d) u = scn[t - d];
        __syncthreads();
        if (t < 256) scn[t] += u;
        __syncthreads();
    }
    if (t < NBUCK) {
        int excl = scn[t] - cnt[t];
        lofs[t] = excl;
        lcur[t] = excl;
        gbase[t] = atomicAdd(&gcur[t], cnt[t]);   // 196 global atomics/block
    }
    __syncthreads();
    for (int i = t; i < EPB; i += 1024) {
        unsigned int e = ep[i];
        int p = atomicAdd(&lcur[e >> 24], 1);
        ep2[p] = e;
    }
    __syncthreads();
    for (int i = t; i < EPB; i += 1024) {
        unsigned int e = ep2[i];
        int bb = e >> 24;
        int gp = gbase[bb] + (i - lofs[bb]);
        if (gp < (bb + 1) * BCAP) padded[gp] = e;  // overflow guard (never fires)
    }
}

// ---------------- Edge-parallel bucket gather + next-layer GEMM ----------------
// Block = one 256-node bucket. hacc[256][20] in LDS accumulates agg + root term,
// then the 20x20 GEMM runs from LDS.

__global__ __launch_bounds__(1024) void bgather_gemm(const int* __restrict__ gcur,
        const unsigned int* __restrict__ padded,
        const float* __restrict__ y_in, const float* __restrict__ accp,
        const float* __restrict__ Wrel, const float* __restrict__ Wroot,
        const float* __restrict__ b,
        float* __restrict__ y_out, float* __restrict__ acc_out) {
    __shared__ float sWrel[HID * HID];
    __shared__ float sWroot[HID * HID];
    __shared__ float sb[HID];
    __shared__ float hacc[256 * HID];   // 20 KB
    int g = blockIdx.x, t = threadIdx.x;
    int base = g * BCAP;
    int m = min(gcur[g] - base, BCAP);
    int n0 = g * 256;
    int nvalid = min(256, N_NODES - n0);
    for (int i = t; i < HID * HID; i += 1024) { sWrel[i] = Wrel[i]; sWroot[i] = Wroot[i]; }
    if (t < HID) sb[t] = b[t];
    for (int i = t; i < nvalid * HID; i += 1024) hacc[i] = accp[n0 * HID + i];
    __syncthreads();
    if (t < NGRP * 5) {
        int grp = t / 5, q4 = (t % 5) * 4;
        int s = grp;
        for (; s + 3 * NGRP < m; s += 4 * NGRP) {
            unsigned int e0 = padded[base + s];
            unsigned int e1 = padded[base + s + NGRP];
            unsigned int e2 = padded[base + s + 2 * NGRP];
            unsigned int e3 = padded[base + s + 3 * NGRP];
            float4 v0 = *(const float4*)(y_in + (e0 & 0xFFFFu) * HID + q4);
            float4 v1 = *(const float4*)(y_in + (e1 & 0xFFFFu) * HID + q4);
            float4 v2 = *(const float4*)(y_in + (e2 & 0xFFFFu) * HID + q4);
            float4 v3 = *(const float4*)(y_in + (e3 & 0xFFFFu) * HID + q4);
            int l0 = ((e0 >> 16) & 255u) * HID + q4;
            int l1 = ((e1 >> 16) & 255u) * HID + q4;
            int l2 = ((e2 >> 16) & 255u) * HID + q4;
            int l3 = ((e3 >> 16) & 255u) * HID + q4;
            atomicAdd(&hacc[l0 + 0], v0.x); atomicAdd(&hacc[l0 + 1], v0.y);
            atomicAdd(&hacc[l0 + 2], v0.z); atomicAdd(&hacc[l0 + 3], v0.w);
            atomicAdd(&hacc[l1 + 0], v1.x); atomicAdd(&hacc[l1 + 1], v1.y);
            atomicAdd(&hacc[l1 + 2], v1.z); atomicAdd(&hacc[l1 + 3], v1.w);
            atomicAdd(&hacc[l2 + 0], v2.x); atomicAdd(&hacc[l2 + 1], v2.y);
            atomicAdd(&hacc[l2 + 2], v2.z); atomicAdd(&hacc[l2 + 3], v2.w);
            atomicAdd(&hacc[l3 + 0], v3.x); atomicAdd(&hacc[l3 + 1], v3.y);
            atomicAdd(&hacc[l3 + 2], v3.z); atomicAdd(&hacc[l3 + 3], v3.w);
        }
        for (; s < m; s += NGRP) {
            unsigned int e = padded[base + s];
            float4 v = *(const float4*)(y_in + (e & 0xFFFFu) * HID + q4);
            int l = ((e >> 16) & 255u) * HID + q4;
            atomicAdd(&hacc[l + 0], v.x); atomicAdd(&hacc[l + 1], v.y);
            atomicAdd(&hacc[l + 2], v.z); atomicAdd(&hacc[l + 3], v.w);
        }
    }
    __syncthreads();
    // GEMM from LDS: 1280 output-quads (y and acc together)
    for (int i = t; i < nvalid * 5; i += 1024) {
        int n = i / 5, j0 = (i % 5) * 4;
        float y0 = 0.f, y1 = 0.f, y2 = 0.f, y3 = 0.f;
        float a0 = sb[j0], a1 = sb[j0 + 1], a2 = sb[j0 + 2], a3 = sb[j0 + 3];
        #pragma unroll
        for (int k = 0; k < HID; ++k) {
            float h = fmaxf(hacc[n * HID + k], 0.f);
            const float* wr = sWrel  + k * HID + j0;
            const float* wo = sWroot + k * HID + j0;
            y0 = fmaf(h, wr[0], y0); y1 = fmaf(h, wr[1], y1);
            y2 = fmaf(h, wr[2], y2); y3 = fmaf(h, wr[3], y3);
            a0 = fmaf(h, wo[0], a0); a1 = fmaf(h, wo[1], a1);
            a2 = fmaf(h, wo[2], a2); a3 = fmaf(h, wo[3], a3);
        }
        *(float4*)(y_out   + (n0 + n) * HID + j0) = make_float4(y0, y1, y2, y3);
        *(float4*)(acc_out + (n0 + n) * HID + j0) = make_float4(a0, a1, a2, a3);
    }
}

// ---------------- Edge-parallel bucket gather + pooling partials ----------------

__global__ __launch_bounds__(1024) void bgather_pool(const int* __restrict__ gcur,
        const unsigned int* __restrict__ padded,
        const float* __restrict__ y_in, const float* __restrict__ accp,
        const int* __restrict__ batch,
        float* __restrict__ gmax, float* __restrict__ gsum, float* __restrict__ gcnt) {
    __shared__ float hacc[256 * HID];   // 20 KB
    __shared__ float pmax[32 * HID];
    __shared__ float psum[32 * HID];
    __shared__ int   lcnt[32];
    __shared__ int   sbatch[256];
    int g = blockIdx.x, t = threadIdx.x;
    int base = g * BCAP;
    int m = min(gcur[g] - base, BCAP);
    int n0 = g * 256;
    int nvalid = min(256, N_NODES - n0);
    for (int i = t; i < nvalid * HID; i += 1024) hacc[i] = accp[n0 * HID + i];
    for (int i = t; i < 32 * HID; i += 1024) { pmax[i] = 0.f; psum[i] = 0.f; }
    if (t < 32) lcnt[t] = 0;
    if (t < nvalid) sbatch[t] = batch[n0 + t];
    __syncthreads();
    if (t < NGRP * 5) {
        int grp = t / 5, q4 = (t % 5) * 4;
        int s = grp;
        for (; s + 3 * NGRP < m; s += 4 * NGRP) {
            unsigned int e0 = padded[base + s];
            unsigned int e1 = padded[base + s + NGRP];
            unsigned int e2 = padded[base + s + 2 * NGRP];
            unsigned int e3 = padded[base + s + 3 * NGRP];
            float4 v0 = *(const float4*)(y_in + (e0 & 0xFFFFu) * HID + q4);
            float4 v1 = *(const float4*)(y_in + (e1 & 0xFFFFu) * HID + q4);
            float4 v2 = *(const float4*)(y_in + (e2 & 0xFFFFu) * HID + q4);
            float4 v3 = *(const float4*)(y_in + (e3 & 0xFFFFu) * HID + q4);
            int l0 = ((e0 >> 16) & 255u) * HID + q4;
            int l1 = ((e1 >> 16) & 255u) * HID + q4;
            int l2 = ((e2 >> 16) & 255u) * HID + q4;
            int l3 = ((e3 >> 16) & 255u) * HID + q4;
            atomicAdd(&hacc[l0 + 0], v0.x); atomicAdd(&hacc[l0 + 1], v0.y);
            atomicAdd(&hacc[l0 + 2], v0.z); atomicAdd(&hacc[l0 + 3], v0.w);
            atomicAdd(&hacc[l1 + 0], v1.x); atomicAdd(&hacc[l1 + 1], v1.y);
            atomicAdd(&hacc[l1 + 2], v1.z); atomicAdd(&hacc[l1 + 3], v1.w);
            atomicAdd(&hacc[l2 + 0], v2.x); atomicAdd(&hacc[l2 + 1], v2.y);
            atomicAdd(&hacc[l2 + 2], v2.z); atomicAdd(&hacc[l2 + 3], v2.w);
            atomicAdd(&hacc[l3 + 0], v3.x); atomicAdd(&hacc[l3 + 1], v3.y);
            atomicAdd(&hacc[l3 + 2], v3.z); atomicAdd(&hacc[l3 + 3], v3.w);
        }
        for (; s < m; s += NGRP) {
            unsigned int e = padded[base + s];
            float4 v = *(const float4*)(y_in + (e & 0xFFFFu) * HID + q4);
            int l = ((e >> 16) & 255u) * HID + q4;
            atomicAdd(&hacc[l + 0], v.x); atomicAdd(&hacc[l + 1], v.y);
            atomicAdd(&hacc[l + 2], v.z); atomicAdd(&hacc[l + 3], v.w);
        }
    }
    __syncthreads();
    int g0 = sbatch[0];
    for (int i = t; i < nvalid * HID; i += 1024) {
        int n = i / HID, j = i % HID;
        int li = sbatch[n] - g0;      // span <= a few (graphs ~781 nodes)
        float v = fmaxf(hacc[i], 0.f);
        atomicMax((int*)&pmax[li * HID + j], __float_as_int(v));
        atomicAdd(&psum[li * HID + j], v);
        if (j == 0) atomicAdd(&lcnt[li], 1);
    }
    __syncthreads();
    int span = sbatch[nvalid - 1] - g0 + 1;
    for (int i = t; i < span * HID; i += 1024) {
        atomicMax((int*)&gmax[g0 * HID + i], __float_as_int(pmax[i]));
        atomicAdd(&gsum[g0 * HID + i], psum[i]);
    }
    if (t < span) atomicAdd(&gcnt[g0 + t], (float)lcnt[t]);
}

// ---------------- Final linear on [max || mean] ----------------

__global__ __launch_bounds__(640) void final_lin(const float* __restrict__ gmax,
        const float* __restrict__ gsum, const float* __restrict__ gcnt,
        const float* __restrict__ Wlin, const float* __restrict__ blin,
        float* __restrict__ out) {
    __shared__ float sW[2 * HID * OUT_DIM];
    for (int i = threadIdx.x; i < 2 * HID * OUT_DIM; i += 640) sW[i] = Wlin[i];
    __syncthreads();
    int idx = threadIdx.x;
    if (idx >= N_GRAPHS * OUT_DIM) return;
    int g = idx / OUT_DIM, o = idx % OUT_DIM;
    float c = fmaxf(gcnt[g], 1.0f);
    float a = blin[o];
    #pragma unroll
    for (int j = 0; j < HID; ++j) {
        a = fmaf(gmax[g * HID + j], sW[j * OUT_DIM + o], a);
        a = fmaf(gsum[g * HID + j] / c, sW[(HID + j) * OUT_DIM + o], a);
    }
    out[idx] = a;
}

extern "C" void kernel_launch(void* const* d_in, const int* in_sizes, int n_in,
                              void* d_out, int out_size, void* d_ws, size_t ws_size,
                              hipStream_t stream) {
    const float* x      = (const float*)d_in[0];
    const int*   ei     = (const int*)  d_in[1];
    const int*   batch  = (const int*)  d_in[2];
    const float* Wrel1  = (const float*)d_in[3];
    const float* Wroot1 = (const float*)d_in[4];
    const float* b1     = (const float*)d_in[5];
    const float* Wrel2  = (const float*)d_in[6];
    const float* Wroot2 = (const float*)d_in[7];
    const float* b2     = (const float*)d_in[8];
    const float* Wrel3  = (const float*)d_in[9];
    const float* Wroot3 = (const float*)d_in[10];
    const float* b3     = (const float*)d_in[11];
    const float* Wlin   = (const float*)d_in[12];
    const float* blin   = (const float*)d_in[13];
    float* out = (float*)d_out;

    char* ws = (char*)d_ws;
    const size_t NB = (size_t)N_NODES * HID * sizeof(float);   // 4,000,000 B
    const size_t PB = (size_t)NBUCK * BCAP * sizeof(int);      // 8,028,160 B
    float*        yA     = (float*)(ws);
    float*        yB     = (float*)(ws + NB);
    float*        accA   = (float*)(ws + 2 * NB);
    float*        accB   = (float*)(ws + 3 * NB);
    unsigned int* padded = (unsigned int*)(ws + 4 * NB);
    int*          gcur   = (int*)(ws + 4 * NB + PB);
    float*        gmax   = (float*)(gcur + 256);
    float*        gsum   = gmax + N_GRAPHS * HID;
    float*        gcnt   = gsum + N_GRAPHS * HID;

    const int* src = ei;
    const int* dst = ei + N_EDGES;

    const int gN = (N_NODES * HID + 255) / 256;   // 3907

    // ---- Layer 1 GEMM (+ init gcur/gmax/gsum/gcnt) ----
    gemm50<<<gN, 256, 0, stream>>>(x, Wrel1, Wroot1, b1, yA, accA,
                                   gcur, gmax, gsum, gcnt);
    // ---- Bucket scatter (edge grouping by dst>>8) ----
    bucket_scatter<<<256, 1024, 0, stream>>>(dst, src, gcur, padded);
    // ---- L1 gather + L2 GEMM ----
    bgather_gemm<<<NBUCK, 1024, 0, stream>>>(gcur, padded, yA, accA,
                                             Wrel2, Wroot2, b2, yB, accB);
    // ---- L2 gather + L3 GEMM ----
    bgather_gemm<<<NBUCK, 1024, 0, stream>>>(gcur, padded, yB, accB,
                                             Wrel3, Wroot3, b3, yA, accA);
    // ---- L3 gather + pooling partials ----
    bgather_pool<<<NBUCK, 1024, 0, stream>>>(gcur, padded, yA, accA, batch,
                                             gmax, gsum, gcnt);
    // ---- final linear ----
    final_lin<<<1, 640, 0, stream>>>(gmax, gsum, gcnt, Wlin, blin, out);
}

// Round 7
// 116.848 us; speedup vs baseline: 5.9718x; 5.9718x over previous
//
#include <hip/hip_runtime.h>

#define N_NODES  50000
#define N_EDGES  1600000
#define N_FEAT   50
#define HID      20
#define OUT_DIM  10
#define N_GRAPHS 64

#define NBUCK 196            // coarse buckets: dst >> 8 (256 nodes each)
#define BCAP  10240          // padded slots/bucket (avg 8163, ~23 sigma margin)
#define EPB   (N_EDGES/256)  // 6250 edges per scatter block
#define G50B  977            // ceil(N_NODES*HID / 1024)

// ================= K1: layer-1 GEMM (+pool init) fused with bucket scatter ==========
// Blocks [0, G50B): gemm50. Blocks [G50B, G50B+256): edge scatter by dst>>8.
// gcur must be zeroed (memsetAsync) before this kernel.

__global__ __launch_bounds__(1024) void k1_gemm_scatter(
        const float* __restrict__ x, const float* __restrict__ Wrel,
        const float* __restrict__ Wroot, const float* __restrict__ b,
        float* __restrict__ y, float* __restrict__ acc,
        const int* __restrict__ dst, const int* __restrict__ srcv,
        int* __restrict__ gcur, unsigned int* __restrict__ padded,
        float* __restrict__ gmax, float* __restrict__ gsum, float* __restrict__ gcnt) {
    __shared__ char smem[55120];
    int t = threadIdx.x;
    if (blockIdx.x < G50B) {
        if (blockIdx.x == 0) {
            for (int i = t; i < N_GRAPHS * HID; i += 1024) { gmax[i] = 0.f; gsum[i] = 0.f; }
            if (t < N_GRAPHS) gcnt[t] = 0.f;
        }
        float* sWrel  = (float*)smem;                 // 1000 floats
        float* sWroot = sWrel + N_FEAT * HID;         // 1000 floats
        for (int i = t; i < N_FEAT * HID; i += 1024) { sWrel[i] = Wrel[i]; sWroot[i] = Wroot[i]; }
        __syncthreads();
        int idx = blockIdx.x * 1024 + t;
        if (idx < N_NODES * HID) {
            int n = idx / HID, j = idx % HID;
            const float* xr = x + n * N_FEAT;
            float a0 = 0.f, a1 = b[j];
            #pragma unroll
            for (int k = 0; k < N_FEAT; ++k) {
                float xv = xr[k];
                a0 = fmaf(xv, sWrel[k * HID + j], a0);
                a1 = fmaf(xv, sWroot[k * HID + j], a1);
            }
            y[idx] = a0; acc[idx] = a1;
        }
    } else {
        unsigned int* ep   = (unsigned int*)smem;     // 6250
        unsigned int* ep2  = ep + EPB;                // 6250
        int* cnt   = (int*)(ep2 + EPB);               // 256
        int* scn   = cnt + 256;
        int* lofs  = scn + 256;
        int* gbase = lofs + 256;
        int* lcur  = gbase + 256;
        if (t < 256) cnt[t] = 0;
        __syncthreads();
        int e0 = (blockIdx.x - G50B) * EPB;
        for (int i = t; i < EPB; i += 1024) {
            int d = dst[e0 + i], s = srcv[e0 + i];
            ep[i] = ((unsigned int)d << 16) | (unsigned int)s;
            atomicAdd(&cnt[d >> 8], 1);
        }
        __syncthreads();
        if (t < 256) scn[t] = cnt[t];
        __syncthreads();
        for (int d = 1; d < 256; d <<= 1) {
            int u = 0;
            if (t < 256 && t >= d) u = scn[t - d];
            __syncthreads();
            if (t < 256) scn[t] += u;
            __syncthreads();
        }
        if (t < NBUCK) {
            int excl = scn[t] - cnt[t];
            lofs[t] = excl; lcur[t] = excl;
            gbase[t] = t * BCAP + atomicAdd(&gcur[t], cnt[t]);
        }
        __syncthreads();
        for (int i = t; i < EPB; i += 1024) {
            unsigned int e = ep[i];
            int p = atomicAdd(&lcur[e >> 24], 1);
            ep2[p] = e;
        }
        __syncthreads();
        for (int i = t; i < EPB; i += 1024) {
            unsigned int e = ep2[i];
            int bb = e >> 24;
            int gp = gbase[bb] + (i - lofs[bb]);
            if (gp < (bb + 1) * BCAP) padded[gp] = e;   // overflow guard (never fires)
        }
    }
}

// ================= K2: per-bucket counting sort + LPT perm + gather1 + gemm2 =========
// Block = one 256-node bucket, 1024 threads. Sorted csr kept in LDS for the
// fused gather; csr16/start/cnt/perm written to global for K3/K4.

__global__ __launch_bounds__(1024) void k2_build_gather(
        const int* __restrict__ gcur, const unsigned int* __restrict__ padded,
        unsigned short* __restrict__ csr16, int* __restrict__ startg,
        int* __restrict__ cntg, unsigned short* __restrict__ permg,
        const float* __restrict__ y_in, const float* __restrict__ accp,
        const float* __restrict__ Wrel, const float* __restrict__ Wroot,
        const float* __restrict__ b,
        float* __restrict__ y_out, float* __restrict__ acc_out) {
    __shared__ unsigned short eo[BCAP];        // 20 KB sorted csr (LDS-resident)
    __shared__ float rh[256 * HID];            // 20 KB agg + root accumulator
    __shared__ float sWrel[HID * HID], sWroot[HID * HID], sb[HID];
    __shared__ int cnt4[4][256], cur4[4][256];
    __shared__ int scn[256], s_start[256], s_cnt[256];
    __shared__ unsigned short sperm[256];
    int g = blockIdx.x, t = threadIdx.x, wg = t >> 8;
    int base = g * BCAP;
    int m = min(gcur[g], BCAP);
    int n0 = g * 256, nvalid = min(256, N_NODES - n0);
    for (int i = t; i < HID * HID; i += 1024) { sWrel[i] = Wrel[i]; sWroot[i] = Wroot[i]; }
    if (t < HID) sb[t] = b[t];
    if (t < 256) { cnt4[0][t] = 0; cnt4[1][t] = 0; cnt4[2][t] = 0; cnt4[3][t] = 0; }
    for (int i = t; i < nvalid * HID; i += 1024) rh[i] = accp[n0 * HID + i];
    __syncthreads();
    // histogram (4-way privatized)
    for (int i = t; i < m; i += 1024)
        atomicAdd(&cnt4[wg][(padded[base + i] >> 16) & 255u], 1);
    __syncthreads();
    int c0 = 0, c1 = 0, c2 = 0, tot = 0;
    if (t < 256) {
        c0 = cnt4[0][t]; c1 = cnt4[1][t]; c2 = cnt4[2][t]; int c3 = cnt4[3][t];
        tot = c0 + c1 + c2 + c3;
        scn[t] = tot; s_cnt[t] = tot;
    }
    __syncthreads();
    for (int d = 1; d < 256; d <<= 1) {
        int u = 0;
        if (t < 256 && t >= d) u = scn[t - d];
        __syncthreads();
        if (t < 256) scn[t] += u;
        __syncthreads();
    }
    if (t < 256) {
        int excl = scn[t] - tot;
        s_start[t] = excl;
        cur4[0][t] = excl; cur4[1][t] = excl + c0;
        cur4[2][t] = excl + c0 + c1; cur4[3][t] = excl + c0 + c1 + c2;
        int node = n0 + t;
        if (node < N_NODES) { startg[node] = base + excl; cntg[node] = tot; }
    }
    __syncthreads();
    // place (grouped by node)
    for (int i = t; i < m; i += 1024) {
        unsigned int e = padded[base + i];
        int p = atomicAdd(&cur4[wg][(e >> 16) & 255u], 1);
        eo[p] = (unsigned short)(e & 0xFFFFu);
    }
    __syncthreads();
    for (int i = t; i < m; i += 1024) csr16[base + i] = eo[i];  // coalesced
    // degree-descending permutation (rank by comparison, no atomics)
    if (t < 256) {
        int d = s_cnt[t], rank = 0;
        for (int j2 = 0; j2 < 256; ++j2) {
            int dj = s_cnt[j2];
            rank += (dj > d) || (dj == d && j2 < t);
        }
        sperm[rank] = (unsigned short)t;
    }
    __syncthreads();
    if (t < 256) permg[n0 + t] = sperm[t];
    // LPT-paired gather: group g takes ranks g (heavy) and 255-g (light)
    int grp = t >> 3, lane = t & 7;
    if (lane < 5) {
        int q4 = lane * 4;
        #pragma unroll
        for (int rep = 0; rep < 2; ++rep) {
            int rank = rep ? 255 - grp : grp;
            int nl = sperm[rank];
            if (nl >= nvalid) continue;
            int a = s_start[nl], e = a + s_cnt[nl];
            float4 s0 = make_float4(0.f, 0.f, 0.f, 0.f);
            float4 s1 = make_float4(0.f, 0.f, 0.f, 0.f);
            int k = a;
            for (; k + 3 < e; k += 4) {
                int sn0 = eo[k], sn1 = eo[k + 1], sn2 = eo[k + 2], sn3 = eo[k + 3];
                float4 v0 = *(const float4*)(y_in + sn0 * HID + q4);
                float4 v1 = *(const float4*)(y_in + sn1 * HID + q4);
                float4 v2 = *(const float4*)(y_in + sn2 * HID + q4);
                float4 v3 = *(const float4*)(y_in + sn3 * HID + q4);
                s0.x += v0.x + v2.x; s0.y += v0.y + v2.y;
                s0.z += v0.z + v2.z; s0.w += v0.w + v2.w;
                s1.x += v1.x + v3.x; s1.y += v1.y + v3.y;
                s1.z += v1.z + v3.z; s1.w += v1.w + v3.w;
            }
            for (; k < e; ++k) {
                int sn = eo[k];
                float4 v = *(const float4*)(y_in + sn * HID + q4);
                s0.x += v.x; s0.y += v.y; s0.z += v.z; s0.w += v.w;
            }
            float* rp = &rh[nl * HID + q4];   // exclusive owner: plain RMW
            rp[0] += s0.x + s1.x; rp[1] += s0.y + s1.y;
            rp[2] += s0.z + s1.z; rp[3] += s0.w + s1.w;
        }
    }
    __syncthreads();
    // next-layer GEMM from LDS
    for (int i = t; i < nvalid * 5; i += 1024) {
        int n = i / 5, j0 = (i % 5) * 4;
        float y0 = 0.f, y1 = 0.f, y2 = 0.f, y3 = 0.f;
        float a0 = sb[j0], a1 = sb[j0 + 1], a2 = sb[j0 + 2], a3 = sb[j0 + 3];
        #pragma unroll
        for (int k = 0; k < HID; ++k) {
            float h = fmaxf(rh[n * HID + k], 0.f);
            const float* wr = sWrel  + k * HID + j0;
            const float* wo = sWroot + k * HID + j0;
            y0 = fmaf(h, wr[0], y0); y1 = fmaf(h, wr[1], y1);
            y2 = fmaf(h, wr[2], y2); y3 = fmaf(h, wr[3], y3);
            a0 = fmaf(h, wo[0], a0); a1 = fmaf(h, wo[1], a1);
            a2 = fmaf(h, wo[2], a2); a3 = fmaf(h, wo[3], a3);
        }
        *(float4*)(y_out   + (n0 + n) * HID + j0) = make_float4(y0, y1, y2, y3);
        *(float4*)(acc_out + (n0 + n) * HID + j0) = make_float4(a0, a1, a2, a3);
    }
}

// ================= K3: gather (global csr, LPT perm) + gemm3 ========================

__global__ __launch_bounds__(1024) void k3_gather_gemm(
        const int* __restrict__ startg, const int* __restrict__ cntg,
        const unsigned short* __restrict__ csr16, const unsigned short* __restrict__ permg,
        const float* __restrict__ y_in, const float* __restrict__ accp,
        const float* __restrict__ Wrel, const float* __restrict__ Wroot,
        const float* __restrict__ b,
        float* __restrict__ y_out, float* __restrict__ acc_out) {
    __shared__ float rh[256 * HID];
    __shared__ float sWrel[HID * HID], sWroot[HID * HID], sb[HID];
    int g = blockIdx.x, t = threadIdx.x;
    int n0 = g * 256, nvalid = min(256, N_NODES - n0);
    for (int i = t; i < HID * HID; i += 1024) { sWrel[i] = Wrel[i]; sWroot[i] = Wroot[i]; }
    if (t < HID) sb[t] = b[t];
    for (int i = t; i < nvalid * HID; i += 1024) rh[i] = accp[n0 * HID + i];
    __syncthreads();
    int grp = t >> 3, lane = t & 7;
    if (lane < 5) {
        int q4 = lane * 4;
        #pragma unroll
        for (int rep = 0; rep < 2; ++rep) {
            int rank = rep ? 255 - grp : grp;
            int nl = permg[n0 + rank];
            if (nl >= nvalid) continue;
            int node = n0 + nl;
            int a = startg[node], e = a + cntg[node];
            float4 s0 = make_float4(0.f, 0.f, 0.f, 0.f);
            float4 s1 = make_float4(0.f, 0.f, 0.f, 0.f);
            int k = a;
            for (; k + 3 < e; k += 4) {
                int sn0 = csr16[k], sn1 = csr16[k + 1], sn2 = csr16[k + 2], sn3 = csr16[k + 3];
                float4 v0 = *(const float4*)(y_in + sn0 * HID + q4);
                float4 v1 = *(const float4*)(y_in + sn1 * HID + q4);
                float4 v2 = *(const float4*)(y_in + sn2 * HID + q4);
                float4 v3 = *(const float4*)(y_in + sn3 * HID + q4);
                s0.x += v0.x + v2.x; s0.y += v0.y + v2.y;
                s0.z += v0.z + v2.z; s0.w += v0.w + v2.w;
                s1.x += v1.x + v3.x; s1.y += v1.y + v3.y;
                s1.z += v1.z + v3.z; s1.w += v1.w + v3.w;
            }
            for (; k < e; ++k) {
                int sn = csr16[k];
                float4 v = *(const float4*)(y_in + sn * HID + q4);
                s0.x += v.x; s0.y += v.y; s0.z += v.z; s0.w += v.w;
            }
            float* rp = &rh[nl * HID + q4];
            rp[0] += s0.x + s1.x; rp[1] += s0.y + s1.y;
            rp[2] += s0.z + s1.z; rp[3] += s0.w + s1.w;
        }
    }
    __syncthreads();
    for (int i = t; i < nvalid * 5; i += 1024) {
        int n = i / 5, j0 = (i % 5) * 4;
        float y0 = 0.f, y1 = 0.f, y2 = 0.f, y3 = 0.f;
        float a0 = sb[j0], a1 = sb[j0 + 1], a2 = sb[j0 + 2], a3 = sb[j0 + 3];
        #pragma unroll
        for (int k = 0; k < HID; ++k) {
            float h = fmaxf(rh[n * HID + k], 0.f);
            const float* wr = sWrel  + k * HID + j0;
            const float* wo = sWroot + k * HID + j0;
            y0 = fmaf(h, wr[0], y0); y1 = fmaf(h, wr[1], y1);
            y2 = fmaf(h, wr[2], y2); y3 = fmaf(h, wr[3], y3);
            a0 = fmaf(h, wo[0], a0); a1 = fmaf(h, wo[1], a1);
            a2 = fmaf(h, wo[2], a2); a3 = fmaf(h, wo[3], a3);
        }
        *(float4*)(y_out   + (n0 + n) * HID + j0) = make_float4(y0, y1, y2, y3);
        *(float4*)(acc_out + (n0 + n) * HID + j0) = make_float4(a0, a1, a2, a3);
    }
}

// ================= K4: gather + segment tree-reduce pooling =========================

__global__ __launch_bounds__(1024) void k4_gather_pool(
        const int* __restrict__ startg, const int* __restrict__ cntg,
        const unsigned short* __restrict__ csr16, const unsigned short* __restrict__ permg,
        const float* __restrict__ y_in, const float* __restrict__ accp,
        const int* __restrict__ batch,
        float* __restrict__ gmax, float* __restrict__ gsum, float* __restrict__ gcnt) {
    __shared__ float rh[256 * HID];            // 20 KB (pre-relu h3)
    __shared__ float redm[51 * HID], reds[51 * HID];
    __shared__ int sbatch[256];
    __shared__ int seglo[16], seghi[16];
    int g = blockIdx.x, t = threadIdx.x;
    int n0 = g * 256, nvalid = min(256, N_NODES - n0);
    for (int i = t; i < nvalid * HID; i += 1024) rh[i] = accp[n0 * HID + i];
    if (t < nvalid) sbatch[t] = batch[n0 + t];
    __syncthreads();
    int grp = t >> 3, lane = t & 7;
    if (lane < 5) {
        int q4 = lane * 4;
        #pragma unroll
        for (int rep = 0; rep < 2; ++rep) {
            int rank = rep ? 255 - grp : grp;
            int nl = permg[n0 + rank];
            if (nl >= nvalid) continue;
            int node = n0 + nl;
            int a = startg[node], e = a + cntg[node];
            float4 s0 = make_float4(0.f, 0.f, 0.f, 0.f);
            float4 s1 = make_float4(0.f, 0.f, 0.f, 0.f);
            int k = a;
            for (; k + 3 < e; k += 4) {
                int sn0 = csr16[k], sn1 = csr16[k + 1], sn2 = csr16[k + 2], sn3 = csr16[k + 3];
                float4 v0 = *(const float4*)(y_in + sn0 * HID + q4);
                float4 v1 = *(const float4*)(y_in + sn1 * HID + q4);
                float4 v2 = *(const float4*)(y_in + sn2 * HID + q4);
                float4 v3 = *(const float4*)(y_in + sn3 * HID + q4);
                s0.x += v0.x + v2.x; s0.y += v0.y + v2.y;
                s0.z += v0.z + v2.z; s0.w += v0.w + v2.w;
                s1.x += v1.x + v3.x; s1.y += v1.y + v3.y;
                s1.z += v1.z + v3.z; s1.w += v1.w + v3.w;
            }
            for (; k < e; ++k) {
                int sn = csr16[k];
                float4 v = *(const float4*)(y_in + sn * HID + q4);
                s0.x += v.x; s0.y += v.y; s0.z += v.z; s0.w += v.w;
            }
            float* rp = &rh[nl * HID + q4];
            rp[0] += s0.x + s1.x; rp[1] += s0.y + s1.y;
            rp[2] += s0.z + s1.z; rp[3] += s0.w + s1.w;
        }
    }
    __syncthreads();
    // graph segments within this bucket (span <= 2-3 for ~781-node graphs)
    int g0 = sbatch[0];
    int span = sbatch[nvalid - 1] - g0 + 1;
    if (t < nvalid) {
        int bi = sbatch[t] - g0;
        if (bi < 16) {
            if (t == 0 || sbatch[t - 1] != sbatch[t]) seglo[bi] = t;
            if (t == nvalid - 1 || sbatch[t + 1] != sbatch[t]) seghi[bi] = t + 1;
        }
    }
    __syncthreads();
    if (span > 16) span = 16;  // impossible defensively
    for (int li = 0; li < span; ++li) {
        int lo = seglo[li], hi = seghi[li];
        int r = t / HID, j = t % HID;
        if (r < 51) {
            float mx = 0.f, sm = 0.f;
            for (int n = lo + r; n < hi; n += 51) {
                float v = fmaxf(rh[n * HID + j], 0.f);
                mx = fmaxf(mx, v); sm += v;
            }
            redm[r * HID + j] = mx; reds[r * HID + j] = sm;
        }
        __syncthreads();
        if (t < HID) {
            float mm = 0.f, ss = 0.f;
            #pragma unroll 17
            for (int r2 = 0; r2 < 51; ++r2) {
                mm = fmaxf(mm, redm[r2 * HID + t]);
                ss += reds[r2 * HID + t];
            }
            atomicMax((int*)&gmax[(g0 + li) * HID + t], __float_as_int(mm));
            atomicAdd(&gsum[(g0 + li) * HID + t], ss);
        }
        if (t == HID) atomicAdd(&gcnt[g0 + li], (float)(hi - lo));
        __syncthreads();
    }
}

// ================= K5: final linear on [max || mean] ================================

__global__ __launch_bounds__(640) void final_lin(const float* __restrict__ gmax,
        const float* __restrict__ gsum, const float* __restrict__ gcnt,
        const float* __restrict__ Wlin, const float* __restrict__ blin,
        float* __restrict__ out) {
    __shared__ float sW[2 * HID * OUT_DIM];
    for (int i = threadIdx.x; i < 2 * HID * OUT_DIM; i += 640) sW[i] = Wlin[i];
    __syncthreads();
    int idx = threadIdx.x;
    if (idx >= N_GRAPHS * OUT_DIM) return;
    int g = idx / OUT_DIM, o = idx % OUT_DIM;
    float c = fmaxf(gcnt[g], 1.0f);
    float a = blin[o];
    #pragma unroll
    for (int j = 0; j < HID; ++j) {
        a = fmaf(gmax[g * HID + j], sW[j * OUT_DIM + o], a);
        a = fmaf(gsum[g * HID + j] / c, sW[(HID + j) * OUT_DIM + o], a);
    }
    out[idx] = a;
}

extern "C" void kernel_launch(void* const* d_in, const int* in_sizes, int n_in,
                              void* d_out, int out_size, void* d_ws, size_t ws_size,
                              hipStream_t stream) {
    const float* x      = (const float*)d_in[0];
    const int*   ei     = (const int*)  d_in[1];
    const int*   batch  = (const int*)  d_in[2];
    const float* Wrel1  = (const float*)d_in[3];
    const float* Wroot1 = (const float*)d_in[4];
    const float* b1     = (const float*)d_in[5];
    const float* Wrel2  = (const float*)d_in[6];
    const float* Wroot2 = (const float*)d_in[7];
    const float* b2     = (const float*)d_in[8];
    const float* Wrel3  = (const float*)d_in[9];
    const float* Wroot3 = (const float*)d_in[10];
    const float* b3     = (const float*)d_in[11];
    const float* Wlin   = (const float*)d_in[12];
    const float* blin   = (const float*)d_in[13];
    float* out = (float*)d_out;

    char* ws = (char*)d_ws;
    const size_t NB = (size_t)N_NODES * HID * sizeof(float);          // 4,000,000
    const size_t PB = (size_t)NBUCK * BCAP * sizeof(int);             // 8,028,160
    const size_t CB = (size_t)NBUCK * BCAP * sizeof(unsigned short);  // 4,014,080
    const size_t NP = (size_t)NBUCK * 256;                            // 50,176 padded nodes
    float*          yA     = (float*)(ws);
    float*          yB     = (float*)(ws + NB);
    float*          accA   = (float*)(ws + 2 * NB);
    float*          accB   = (float*)(ws + 3 * NB);
    unsigned int*   padded = (unsigned int*)(ws + 4 * NB);
    unsigned short* csr16  = (unsigned short*)(ws + 4 * NB + PB);
    int*            startg = (int*)(ws + 4 * NB + PB + CB);
    int*            cntg   = startg + NP;
    unsigned short* permg  = (unsigned short*)(cntg + NP);
    int*            gcur   = (int*)((char*)permg + NP * sizeof(unsigned short));
    float*          gmax   = (float*)(gcur + 256);
    float*          gsum   = gmax + N_GRAPHS * HID;
    float*          gcnt   = gsum + N_GRAPHS * HID;

    const int* src = ei;
    const int* dst = ei + N_EDGES;

    // gcur = per-bucket fill counts (zero-based)
    hipMemsetAsync(gcur, 0, NBUCK * sizeof(int), stream);
    // K1: layer-1 GEMM (+ pool-accum init) || bucket scatter
    k1_gemm_scatter<<<G50B + 256, 1024, 0, stream>>>(x, Wrel1, Wroot1, b1, yA, accA,
                                                     dst, src, gcur, padded,
                                                     gmax, gsum, gcnt);
    // K2: bucket counting-sort + perm + L1 gather + L2 GEMM
    k2_build_gather<<<NBUCK, 1024, 0, stream>>>(gcur, padded, csr16, startg, cntg, permg,
                                                yA, accA, Wrel2, Wroot2, b2, yB, accB);
    // K3: L2 gather + L3 GEMM
    k3_gather_gemm<<<NBUCK, 1024, 0, stream>>>(startg, cntg, csr16, permg,
                                               yB, accB, Wrel3, Wroot3, b3, yA, accA);
    // K4: L3 gather + max/mean pooling
    k4_gather_pool<<<NBUCK, 1024, 0, stream>>>(startg, cntg, csr16, permg,
                                               yA, accA, batch, gmax, gsum, gcnt);
    // K5: final linear
    final_lin<<<1, 640, 0, stream>>>(gmax, gsum, gcnt, Wlin, blin, out);
}